// Round 3
// baseline (4899.398 us; speedup 1.0000x reference)
//
#include <hip/hip_runtime.h>
#include <stdint.h>

#define N_TOT 24576
#define B_TOT 4096
#define FEAT  576
#define NCH   192
#define CDIM  4096
#define KD    192

typedef __bf16 bf16x8 __attribute__((ext_vector_type(8)));
typedef float  f32x4  __attribute__((ext_vector_type(4)));

__device__ __forceinline__ float bf2f(unsigned short h) {
    union { unsigned int u; float f; } c; c.u = ((unsigned int)h) << 16; return c.f;
}
__device__ __forceinline__ unsigned short f2bf(float f) {
    union { float f; unsigned int u; } c; c.f = f;
    unsigned int u = c.u;
    u += 0x7fffu + ((u >> 16) & 1u);   // round-to-nearest-even
    return (unsigned short)(u >> 16);
}

// ---------------------------------------------------------------------------
// Prep 1: per-irrep-channel L2 norms for all 4 PE variants.
// S[v][n][192] bf16.  One block per b (6 samples), x[b] staged in LDS.
// ---------------------------------------------------------------------------
__global__ __launch_bounds__(256)
void k_norms(const float* __restrict__ x, unsigned short* __restrict__ S) {
    __shared__ float xs[6][FEAT];
    const int b = blockIdx.x;
    const float* xb = x + (size_t)b * 6 * FEAT;
    for (int idx = threadIdx.x; idx < 6 * FEAT; idx += 256)
        xs[idx / FEAT][idx % FEAT] = xb[idx];
    __syncthreads();
    for (int task = threadIdx.x; task < 6 * NCH; task += 256) {
        const int ch = task % NCH;
        const int ij = task / NCH;
        const int i = ij / 3, j = ij % 3;
        const int l = ch >> 6, c = ch & 63;
        const int d = 2 * l + 1;
        const int off = (l == 0) ? 0 : (l == 1 ? 64 : 256);
        const int f0 = off + c * d;
        const int j1 = (j + 1) % 3, j2 = (j + 2) % 3;
        float ss0 = 0.f, ss1 = 0.f, ss2 = 0.f, ss3 = 0.f;
        for (int m = 0; m < d; ++m) {
            const int f = f0 + m;
            const float a00 = xs[i * 3 + j][f];
            const float a01 = xs[i * 3 + j1][f];
            const float a02 = xs[i * 3 + j2][f];
            const float b00 = xs[(1 - i) * 3 + j][f];
            const float b01 = xs[(1 - i) * 3 + j1][f];
            const float b02 = xs[(1 - i) * 3 + j2][f];
            const float vs = a00;                  // self
            const float vf = 0.5f * (a01 + a02);   // flavor
            const float vn = b00;                  // nunubar
            const float va = 0.5f * (b01 + b02);   // all
            ss0 += vs * vs; ss1 += vf * vf; ss2 += vn * vn; ss3 += va * va;
        }
        const int n = b * 6 + ij;
        const size_t base = (size_t)n * NCH + ch;
        S[0 * (size_t)N_TOT * NCH + base] = f2bf(sqrtf(ss0));
        S[1 * (size_t)N_TOT * NCH + base] = f2bf(sqrtf(ss1));
        S[2 * (size_t)N_TOT * NCH + base] = f2bf(sqrtf(ss2));
        S[3 * (size_t)N_TOT * NCH + base] = f2bf(sqrtf(ss3));
    }
}

// ---------------------------------------------------------------------------
// Prep 2: PE-variant features, TRANSPOSED: XvT[v][f][n] bf16 (n contiguous).
// Tile: 64 samples x 32 features; x slab staged in LDS.
// ---------------------------------------------------------------------------
__global__ __launch_bounds__(256)
void k_xvt(const float* __restrict__ x, unsigned short* __restrict__ XvT) {
    __shared__ float slab[72][33];
    const int n0 = blockIdx.x * 64;
    const int f0 = blockIdx.y * 32;
    const int b0 = n0 / 6;
    const int b1 = (n0 + 63) / 6;
    const int nrows = (b1 - b0 + 1) * 6;
    for (int idx = threadIdx.x; idx < nrows * 32; idx += 256) {
        const int r = idx >> 5, fl = idx & 31;
        const int grow = b0 * 6 + r;
        slab[r][fl] = (grow < N_TOT) ? x[(size_t)grow * FEAT + f0 + fl] : 0.f;
    }
    __syncthreads();
    const int n_l = threadIdx.x & 63;
    const int f_l = threadIdx.x >> 6;   // 0..3
    const int n = n0 + n_l;
    const int b = n / 6, ij = n % 6;
    const int i = ij / 3, j = ij % 3;
    const int rb = (b - b0) * 6;
    const int j1 = (j + 1) % 3, j2 = (j + 2) % 3;
    #pragma unroll
    for (int ii = 0; ii < 8; ++ii) {
        const int fl = f_l + 4 * ii;
        const float a00 = slab[rb + i * 3 + j][fl];
        const float a01 = slab[rb + i * 3 + j1][fl];
        const float a02 = slab[rb + i * 3 + j2][fl];
        const float b00 = slab[rb + (1 - i) * 3 + j][fl];
        const float b01 = slab[rb + (1 - i) * 3 + j1][fl];
        const float b02 = slab[rb + (1 - i) * 3 + j2][fl];
        const size_t o = (size_t)(f0 + fl) * N_TOT + n;
        XvT[0 * (size_t)FEAT * N_TOT + o] = f2bf(a00);
        XvT[1 * (size_t)FEAT * N_TOT + o] = f2bf(0.5f * (a01 + a02));
        XvT[2 * (size_t)FEAT * N_TOT + o] = f2bf(b00);
        XvT[3 * (size_t)FEAT * N_TOT + o] = f2bf(0.5f * (b01 + b02));
    }
}

// ---------------------------------------------------------------------------
// Prep 3: repack weights: W2[(v*3+k)][c = u*64+w][jv = j*64+vv] bf16
// (K-dim jv contiguous, as the MFMA B-operand wants).
// Grid: (64 u, 9 = k*3+j); one launch per variant.
// ---------------------------------------------------------------------------
__global__ __launch_bounds__(256)
void k_w2(const float* __restrict__ Wsrc, unsigned short* __restrict__ W2, int v) {
    __shared__ float tbuf[64][65];
    const int u = blockIdx.x;
    const int kj = blockIdx.y;
    const int k = kj / 3, jj = kj % 3;
    const float* src = Wsrc + ((size_t)(k * 3 + jj) * 64 + u) * 64 * 64;  // [vv][w]
    for (int idx = threadIdx.x; idx < 64 * 64; idx += 256) {
        tbuf[idx >> 6][idx & 63] = src[idx];
    }
    __syncthreads();
    unsigned short* dst = W2 + (size_t)(v * 3 + k) * CDIM * KD;
    for (int idx = threadIdx.x; idx < 64 * 64; idx += 256) {
        const int vv = idx & 63, w = idx >> 6;
        dst[(size_t)(u * 64 + w) * KD + jj * 64 + vv] = f2bf(tbuf[vv][w]);
    }
}

// ---------------------------------------------------------------------------
// Stage-1 GEMM (bf16 MFMA): A[c][n] = sum_jv S[n][jv] * W2[c][jv]
// M = Nc samples, N = 4096 (c = u*64+w), K = 192.  128x128 tile, BK=64,
// 4 waves each computing a 64x64 sub-tile with 16x16x32 MFMAs.
// LDS is reg-staged with a 16B-block XOR swizzle on both write and read.
// ---------------------------------------------------------------------------
__global__ __launch_bounds__(256)
void k_gemm1(const unsigned short* __restrict__ S,
             const unsigned short* __restrict__ W2,
             unsigned short* __restrict__ A,
             int n0, int Nc) {
    __shared__ unsigned short As[128 * 64];
    __shared__ unsigned short Bs[128 * 64];
    const int t = threadIdx.x;
    const int lane = t & 63;
    const int wv = t >> 6;
    const int wr = wv >> 1, wc = wv & 1;
    const unsigned short* Srow = S + (size_t)(n0 + blockIdx.x * 128) * KD;
    const unsigned short* Wrow = W2 + (size_t)(blockIdx.y * 128) * KD;

    const f32x4 zero = {0.f, 0.f, 0.f, 0.f};
    f32x4 acc[4][4];
    #pragma unroll
    for (int a = 0; a < 4; ++a)
        #pragma unroll
        for (int b = 0; b < 4; ++b) acc[a][b] = zero;

    for (int kt = 0; kt < 3; ++kt) {
        if (kt) __syncthreads();
        // Fill 128 rows x 64 k = 1024 x 16B per buffer; 256 threads -> 4 iters.
        #pragma unroll
        for (int it = 0; it < 4; ++it) {
            const int ft = it * 256 + t;
            const int r = ft >> 3, kb = ft & 7;
            const int lds_off = r * 64 + ((kb ^ (r & 7)) << 3);
            *(uint4*)&As[lds_off] = *(const uint4*)(Srow + (size_t)r * KD + kt * 64 + kb * 8);
            *(uint4*)&Bs[lds_off] = *(const uint4*)(Wrow + (size_t)r * KD + kt * 64 + kb * 8);
        }
        __syncthreads();
        #pragma unroll
        for (int s = 0; s < 2; ++s) {
            bf16x8 af[4], bfr[4];
            const int rg = lane & 15;
            const int kb = s * 4 + (lane >> 4);
            #pragma unroll
            for (int mi = 0; mi < 4; ++mi) {
                const int r = wr * 64 + mi * 16 + rg;
                af[mi] = *(const bf16x8*)&As[r * 64 + ((kb ^ (r & 7)) << 3)];
            }
            #pragma unroll
            for (int ni = 0; ni < 4; ++ni) {
                const int r = wc * 64 + ni * 16 + rg;
                bfr[ni] = *(const bf16x8*)&Bs[r * 64 + ((kb ^ (r & 7)) << 3)];
            }
            #pragma unroll
            for (int mi = 0; mi < 4; ++mi)
                #pragma unroll
                for (int ni = 0; ni < 4; ++ni)
                    acc[mi][ni] = __builtin_amdgcn_mfma_f32_16x16x32_bf16(
                        af[mi], bfr[ni], acc[mi][ni], 0, 0, 0);
        }
    }
    // Epilogue: C row = (lane>>4)*4 + reg (sample), col = lane&15 (c).
    // A layout [c][n]: 4 consecutive samples per lane -> 8B packed store.
    const int colg = lane & 15;
    const int rg4 = (lane >> 4) << 2;
    #pragma unroll
    for (int ni = 0; ni < 4; ++ni) {
        const int c = blockIdx.y * 128 + wc * 64 + ni * 16 + colg;
        #pragma unroll
        for (int mi = 0; mi < 4; ++mi) {
            const int nl = blockIdx.x * 128 + wr * 64 + mi * 16 + rg4;
            ushort4 pk;
            pk.x = f2bf(acc[mi][ni][0]);
            pk.y = f2bf(acc[mi][ni][1]);
            pk.z = f2bf(acc[mi][ni][2]);
            pk.w = f2bf(acc[mi][ni][3]);
            *(ushort4*)&A[(size_t)c * Nc + nl] = pk;
        }
    }
}

// ---------------------------------------------------------------------------
// Stage-2: yT[f][n] (+)= COEF * sum_u A[u*64+w][n] * XvT[koff+u*DK+m][n]
// One thread per sample; all loads coalesced along n.
// ---------------------------------------------------------------------------
template<int DK, int WC>
__global__ __launch_bounds__(256)
void k_gemm2(const unsigned short* __restrict__ A,
             const unsigned short* __restrict__ XvT,
             float* __restrict__ yT,
             int n0, int Nc, int koff, int accum) {
    const int nl = blockIdx.x * 256 + threadIdx.x;
    const int n = n0 + nl;
    const int w0 = blockIdx.y * WC;
    float acc[WC * DK];
    #pragma unroll
    for (int i = 0; i < WC * DK; ++i) acc[i] = 0.f;
    for (int u = 0; u < 64; ++u) {
        float xv[DK];
        #pragma unroll
        for (int m = 0; m < DK; ++m)
            xv[m] = bf2f(XvT[(size_t)(koff + u * DK + m) * N_TOT + n]);
        #pragma unroll
        for (int w = 0; w < WC; ++w) {
            const float a = bf2f(A[(size_t)(u * 64 + w0 + w) * Nc + nl]);
            #pragma unroll
            for (int m = 0; m < DK; ++m)
                acc[w * DK + m] += a * xv[m];
        }
    }
    const float COEF = 0.009021097956f;  // 1/sqrt(12288)
    #pragma unroll
    for (int w = 0; w < WC; ++w)
        #pragma unroll
        for (int m = 0; m < DK; ++m) {
            const size_t o = (size_t)(koff + (w0 + w) * DK + m) * N_TOT + n;
            float val = COEF * acc[w * DK + m];
            if (accum) val += yT[o];
            yT[o] = val;
        }
}

// ---------------------------------------------------------------------------
// Final: transpose yT[576][N] -> out[N][576].
// ---------------------------------------------------------------------------
__global__ __launch_bounds__(256)
void k_out(const float* __restrict__ yT, float* __restrict__ out) {
    __shared__ float tl[32][65];
    const int n0 = blockIdx.x * 64;
    const int f0 = blockIdx.y * 32;
    const int t = threadIdx.x;
    const int nl = t & 63, flb = t >> 6;
    #pragma unroll
    for (int ii = 0; ii < 8; ++ii) {
        const int fl = flb * 8 + ii;
        tl[fl][nl] = yT[(size_t)(f0 + fl) * N_TOT + n0 + nl];
    }
    __syncthreads();
    const int c = t & 31, rb = t >> 5;
    #pragma unroll
    for (int jj = 0; jj < 8; ++jj) {
        const int r = rb * 8 + jj;
        out[(size_t)(n0 + r) * FEAT + f0 + c] = tl[c][r];
    }
}

// ---------------------------------------------------------------------------
extern "C" void kernel_launch(void* const* d_in, const int* in_sizes, int n_in,
                              void* d_out, int out_size, void* d_ws, size_t ws_size,
                              hipStream_t stream) {
    const float* x = (const float*)d_in[0];
    float* out = (float*)d_out;

    char* ws = (char*)d_ws;
    size_t off = 0;
    unsigned short* S   = (unsigned short*)(ws + off); off += (size_t)4 * N_TOT * NCH * 2;   // 37.7 MB
    unsigned short* XvT = (unsigned short*)(ws + off); off += (size_t)4 * FEAT * N_TOT * 2;  // 113.2 MB
    unsigned short* W2  = (unsigned short*)(ws + off); off += (size_t)12 * CDIM * KD * 2;    // 18.9 MB
    float* yT           = (float*)(ws + off);          off += (size_t)FEAT * N_TOT * 4;      // 56.6 MB
    unsigned short* A   = (unsigned short*)(ws + off);

    // Size the A slot from remaining workspace; chunk samples if needed.
    int Nc = 256;
    if (ws_size > off) {
        long long cap = (long long)(ws_size - off) / (CDIM * 2);
        cap = (cap / 256) * 256;
        if (cap > N_TOT) cap = N_TOT;
        if (cap >= 256) Nc = (int)cap;
    }

    k_norms<<<dim3(B_TOT), 256, 0, stream>>>(x, S);
    k_xvt<<<dim3(N_TOT / 64, FEAT / 32), 256, 0, stream>>>(x, XvT);
    for (int v = 0; v < 4; ++v)
        k_w2<<<dim3(64, 9), 256, 0, stream>>>((const float*)d_in[1 + v], W2, v);

    for (int c0 = 0; c0 < N_TOT; c0 += Nc) {
        int nc = N_TOT - c0; if (nc > Nc) nc = Nc;
        for (int v = 0; v < 4; ++v) {
            const unsigned short* Sv = S + (size_t)v * N_TOT * NCH;
            const unsigned short* Xv = XvT + (size_t)v * FEAT * N_TOT;
            for (int k = 0; k < 3; ++k) {
                const unsigned short* Wvk = W2 + (size_t)(v * 3 + k) * CDIM * KD;
                k_gemm1<<<dim3(nc / 128, 32), 256, 0, stream>>>(Sv, Wvk, A, c0, nc);
                if (k == 0)
                    k_gemm2<1, 32><<<dim3(nc / 256, 2), 256, 0, stream>>>(A, Xv, yT, c0, nc, 0, v > 0);
                else if (k == 1)
                    k_gemm2<3, 16><<<dim3(nc / 256, 4), 256, 0, stream>>>(A, Xv, yT, c0, nc, 64, v > 0);
                else
                    k_gemm2<5, 8><<<dim3(nc / 256, 8), 256, 0, stream>>>(A, Xv, yT, c0, nc, 256, v > 0);
            }
        }
    }
    k_out<<<dim3(N_TOT / 64, FEAT / 32), 256, 0, stream>>>(yT, out);
}

// Round 4
// 2556.227 us; speedup vs baseline: 1.9167x; 1.9167x over previous
//
#include <hip/hip_runtime.h>
#include <stdint.h>

#define N_TOT 24576
#define B_TOT 4096
#define FEAT  576
#define NCH   192
#define CDIM  4096
#define KD    192

typedef __bf16 bf16x8 __attribute__((ext_vector_type(8)));
typedef float  f32x4  __attribute__((ext_vector_type(4)));

__device__ __forceinline__ float bf2f(unsigned short h) {
    union { unsigned int u; float f; } c; c.u = ((unsigned int)h) << 16; return c.f;
}
__device__ __forceinline__ unsigned short f2bf(float f) {
    union { float f; unsigned int u; } c; c.f = f;
    unsigned int u = c.u;
    u += 0x7fffu + ((u >> 16) & 1u);   // round-to-nearest-even
    return (unsigned short)(u >> 16);
}

// ---------------------------------------------------------------------------
// Prep 1: per-irrep-channel L2 norms for all 4 PE variants.
// S[v][n][192] bf16.  One block per b (6 samples), x[b] staged in LDS.
// ---------------------------------------------------------------------------
__global__ __launch_bounds__(256)
void k_norms(const float* __restrict__ x, unsigned short* __restrict__ S) {
    __shared__ float xs[6][FEAT];
    const int b = blockIdx.x;
    const float* xb = x + (size_t)b * 6 * FEAT;
    for (int idx = threadIdx.x; idx < 6 * FEAT; idx += 256)
        xs[idx / FEAT][idx % FEAT] = xb[idx];
    __syncthreads();
    for (int task = threadIdx.x; task < 6 * NCH; task += 256) {
        const int ch = task % NCH;
        const int ij = task / NCH;
        const int i = ij / 3, j = ij % 3;
        const int l = ch >> 6, c = ch & 63;
        const int d = 2 * l + 1;
        const int off = (l == 0) ? 0 : (l == 1 ? 64 : 256);
        const int f0 = off + c * d;
        const int j1 = (j + 1) % 3, j2 = (j + 2) % 3;
        float ss0 = 0.f, ss1 = 0.f, ss2 = 0.f, ss3 = 0.f;
        for (int m = 0; m < d; ++m) {
            const int f = f0 + m;
            const float a00 = xs[i * 3 + j][f];
            const float a01 = xs[i * 3 + j1][f];
            const float a02 = xs[i * 3 + j2][f];
            const float b00 = xs[(1 - i) * 3 + j][f];
            const float b01 = xs[(1 - i) * 3 + j1][f];
            const float b02 = xs[(1 - i) * 3 + j2][f];
            const float vs = a00;                  // self
            const float vf = 0.5f * (a01 + a02);   // flavor
            const float vn = b00;                  // nunubar
            const float va = 0.5f * (b01 + b02);   // all
            ss0 += vs * vs; ss1 += vf * vf; ss2 += vn * vn; ss3 += va * va;
        }
        const int n = b * 6 + ij;
        const size_t base = (size_t)n * NCH + ch;
        S[0 * (size_t)N_TOT * NCH + base] = f2bf(sqrtf(ss0));
        S[1 * (size_t)N_TOT * NCH + base] = f2bf(sqrtf(ss1));
        S[2 * (size_t)N_TOT * NCH + base] = f2bf(sqrtf(ss2));
        S[3 * (size_t)N_TOT * NCH + base] = f2bf(sqrtf(ss3));
    }
}

// ---------------------------------------------------------------------------
// Prep 2 (per chunk): PE-variant features, TRANSPOSED chunk-local:
// XvTc[v][f][nc] bf16 (local n contiguous).  Tile: 64 samples x 32 features.
// ---------------------------------------------------------------------------
__global__ __launch_bounds__(256)
void k_xvt(const float* __restrict__ x, unsigned short* __restrict__ XvTc,
           int c0, int nc) {
    __shared__ float slab[72][33];
    const int n0 = c0 + blockIdx.x * 64;   // absolute sample index
    const int f0 = blockIdx.y * 32;
    const int b0 = n0 / 6;
    const int b1 = (n0 + 63) / 6;
    const int nrows = (b1 - b0 + 1) * 6;   // <= 72
    for (int idx = threadIdx.x; idx < nrows * 32; idx += 256) {
        const int r = idx >> 5, fl = idx & 31;
        const int grow = b0 * 6 + r;
        slab[r][fl] = (grow < N_TOT) ? x[(size_t)grow * FEAT + f0 + fl] : 0.f;
    }
    __syncthreads();
    const int n_l = threadIdx.x & 63;
    const int f_l = threadIdx.x >> 6;   // 0..3
    const int n = n0 + n_l;             // absolute
    const int b = n / 6, ij = n % 6;
    const int i = ij / 3, j = ij % 3;
    const int rb = (b - b0) * 6;
    const int j1 = (j + 1) % 3, j2 = (j + 2) % 3;
    const size_t vstride = (size_t)FEAT * nc;
    #pragma unroll
    for (int ii = 0; ii < 8; ++ii) {
        const int fl = f_l + 4 * ii;
        const float a00 = slab[rb + i * 3 + j][fl];
        const float a01 = slab[rb + i * 3 + j1][fl];
        const float a02 = slab[rb + i * 3 + j2][fl];
        const float b00 = slab[rb + (1 - i) * 3 + j][fl];
        const float b01 = slab[rb + (1 - i) * 3 + j1][fl];
        const float b02 = slab[rb + (1 - i) * 3 + j2][fl];
        const size_t o = (size_t)(f0 + fl) * nc + (n - c0);
        XvTc[0 * vstride + o] = f2bf(a00);
        XvTc[1 * vstride + o] = f2bf(0.5f * (a01 + a02));
        XvTc[2 * vstride + o] = f2bf(b00);
        XvTc[3 * vstride + o] = f2bf(0.5f * (b01 + b02));
    }
}

// ---------------------------------------------------------------------------
// Prep 3: repack weights (all 4 variants in one dispatch, blockIdx.z = v):
// W2[(v*3+k)][c = u*64+w][jv = j*64+vv] bf16 (K-dim contiguous).
// ---------------------------------------------------------------------------
__global__ __launch_bounds__(256)
void k_w2(const float* __restrict__ Wa, const float* __restrict__ Wb,
          const float* __restrict__ Wc, const float* __restrict__ Wd,
          unsigned short* __restrict__ W2) {
    __shared__ float tbuf[64][65];
    const int v = blockIdx.z;
    const float* srcs[4] = {Wa, Wb, Wc, Wd};
    const float* Wsrc = srcs[v];
    const int u = blockIdx.x;
    const int kj = blockIdx.y;
    const int k = kj / 3, jj = kj % 3;
    const float* src = Wsrc + ((size_t)(k * 3 + jj) * 64 + u) * 64 * 64;  // [vv][w]
    for (int idx = threadIdx.x; idx < 64 * 64; idx += 256)
        tbuf[idx >> 6][idx & 63] = src[idx];
    __syncthreads();
    unsigned short* dst = W2 + (size_t)(v * 3 + k) * CDIM * KD;
    for (int idx = threadIdx.x; idx < 64 * 64; idx += 256) {
        const int vv = idx & 63, w = idx >> 6;
        dst[(size_t)(u * 64 + w) * KD + jj * 64 + vv] = f2bf(tbuf[vv][w]);
    }
}

// ---------------------------------------------------------------------------
// Stage-1 GEMM (bf16 MFMA): A[c][nl] = sum_jv S[n][jv] * W2[c][jv]
// 128x128 tile, BK=64, 4 waves x 64x64 sub-tiles, 16x16x32 MFMA.
// LDS reg-staged with 16B-block XOR swizzle (write+read symmetric).
// ---------------------------------------------------------------------------
__global__ __launch_bounds__(256)
void k_gemm1(const unsigned short* __restrict__ S,
             const unsigned short* __restrict__ W2,
             unsigned short* __restrict__ A,
             int n0, int Nc) {
    __shared__ unsigned short As[128 * 64];
    __shared__ unsigned short Bs[128 * 64];
    const int t = threadIdx.x;
    const int lane = t & 63;
    const int wv = t >> 6;
    const int wr = wv >> 1, wc = wv & 1;
    const unsigned short* Srow = S + (size_t)(n0 + blockIdx.x * 128) * KD;
    const unsigned short* Wrow = W2 + (size_t)(blockIdx.y * 128) * KD;

    const f32x4 zero = {0.f, 0.f, 0.f, 0.f};
    f32x4 acc[4][4];
    #pragma unroll
    for (int a = 0; a < 4; ++a)
        #pragma unroll
        for (int b = 0; b < 4; ++b) acc[a][b] = zero;

    for (int kt = 0; kt < 3; ++kt) {
        if (kt) __syncthreads();
        // 128 rows x 8 chunks of 16B per buffer = 1024 stores; 256 thr -> 4 it.
        #pragma unroll
        for (int it = 0; it < 4; ++it) {
            const int ft = it * 256 + t;
            const int r = ft >> 3, kb = ft & 7;
            const int lds_off = r * 64 + ((kb ^ (r & 7)) << 3);
            *(uint4*)&As[lds_off] = *(const uint4*)(Srow + (size_t)r * KD + kt * 64 + kb * 8);
            *(uint4*)&Bs[lds_off] = *(const uint4*)(Wrow + (size_t)r * KD + kt * 64 + kb * 8);
        }
        __syncthreads();
        #pragma unroll
        for (int s = 0; s < 2; ++s) {
            bf16x8 af[4], bfr[4];
            const int rg = lane & 15;
            const int kb = s * 4 + (lane >> 4);
            #pragma unroll
            for (int mi = 0; mi < 4; ++mi) {
                const int r = wr * 64 + mi * 16 + rg;
                af[mi] = *(const bf16x8*)&As[r * 64 + ((kb ^ (r & 7)) << 3)];
            }
            #pragma unroll
            for (int ni = 0; ni < 4; ++ni) {
                const int r = wc * 64 + ni * 16 + rg;
                bfr[ni] = *(const bf16x8*)&Bs[r * 64 + ((kb ^ (r & 7)) << 3)];
            }
            #pragma unroll
            for (int mi = 0; mi < 4; ++mi)
                #pragma unroll
                for (int ni = 0; ni < 4; ++ni)
                    acc[mi][ni] = __builtin_amdgcn_mfma_f32_16x16x32_bf16(
                        af[mi], bfr[ni], acc[mi][ni], 0, 0, 0);
        }
    }
    // C row = (lane>>4)*4 + reg (sample), col = lane&15 (c); pack 4 -> 8B store.
    const int colg = lane & 15;
    const int rg4 = (lane >> 4) << 2;
    #pragma unroll
    for (int ni = 0; ni < 4; ++ni) {
        const int c = blockIdx.y * 128 + wc * 64 + ni * 16 + colg;
        #pragma unroll
        for (int mi = 0; mi < 4; ++mi) {
            const int nl = blockIdx.x * 128 + wr * 64 + mi * 16 + rg4;
            ushort4 pk;
            pk.x = f2bf(acc[mi][ni][0]);
            pk.y = f2bf(acc[mi][ni][1]);
            pk.z = f2bf(acc[mi][ni][2]);
            pk.w = f2bf(acc[mi][ni][3]);
            *(ushort4*)&A[(size_t)c * Nc + nl] = pk;
        }
    }
}

// ---------------------------------------------------------------------------
// Stage-2: yT[f][n] (+)= COEF * sum_u A[u*64+w][nl] * XvTc[koff+u*DK+m][nl]
// Thread-per-sample, WC=8 w-values per block -> grid (nc/256, 8).
// ---------------------------------------------------------------------------
template<int DK>
__global__ __launch_bounds__(256)
void k_gemm2(const unsigned short* __restrict__ A,
             const unsigned short* __restrict__ XvTc,
             float* __restrict__ yT,
             int c0, int nc, int koff, int accum) {
    const int nl = blockIdx.x * 256 + threadIdx.x;   // chunk-local sample
    const int w0 = blockIdx.y * 8;
    float acc[8 * DK];
    #pragma unroll
    for (int i = 0; i < 8 * DK; ++i) acc[i] = 0.f;
    #pragma unroll 2
    for (int u = 0; u < 64; ++u) {
        float xv[DK];
        #pragma unroll
        for (int m = 0; m < DK; ++m)
            xv[m] = bf2f(XvTc[(size_t)(koff + u * DK + m) * nc + nl]);
        #pragma unroll
        for (int w = 0; w < 8; ++w) {
            const float a = bf2f(A[(size_t)(u * 64 + w0 + w) * nc + nl]);
            #pragma unroll
            for (int m = 0; m < DK; ++m)
                acc[w * DK + m] += a * xv[m];
        }
    }
    const float COEF = 0.009021097956f;  // 1/sqrt(12288)
    #pragma unroll
    for (int w = 0; w < 8; ++w)
        #pragma unroll
        for (int m = 0; m < DK; ++m) {
            const size_t o = (size_t)(koff + (w0 + w) * DK + m) * N_TOT + (c0 + nl);
            float val = COEF * acc[w * DK + m];
            if (accum) val += yT[o];
            yT[o] = val;
        }
}

// ---------------------------------------------------------------------------
// Final: transpose yT[576][N] -> out[N][576].
// ---------------------------------------------------------------------------
__global__ __launch_bounds__(256)
void k_out(const float* __restrict__ yT, float* __restrict__ out) {
    __shared__ float tl[32][65];
    const int n0 = blockIdx.x * 64;
    const int f0 = blockIdx.y * 32;
    const int t = threadIdx.x;
    const int nl = t & 63, flb = t >> 6;
    #pragma unroll
    for (int ii = 0; ii < 8; ++ii) {
        const int fl = flb * 8 + ii;
        tl[fl][nl] = yT[(size_t)(f0 + fl) * N_TOT + n0 + nl];
    }
    __syncthreads();
    const int c = t & 31, rb = t >> 5;
    #pragma unroll
    for (int jj = 0; jj < 8; ++jj) {
        const int r = rb * 8 + jj;
        out[(size_t)(n0 + r) * FEAT + f0 + c] = tl[c][r];
    }
}

// ---------------------------------------------------------------------------
extern "C" void kernel_launch(void* const* d_in, const int* in_sizes, int n_in,
                              void* d_out, int out_size, void* d_ws, size_t ws_size,
                              hipStream_t stream) {
    const float* x = (const float*)d_in[0];
    float* out = (float*)d_out;

    char* ws = (char*)d_ws;
    const size_t szS  = (size_t)4 * N_TOT * NCH * 2;   // 37.7 MB
    const size_t szW2 = (size_t)12 * CDIM * KD * 2;    // 18.9 MB
    const size_t szYT = (size_t)FEAT * N_TOT * 4;      // 56.6 MB
    const size_t fixed = szS + szW2 + szYT;            // 113.2 MB

    // Per-sample chunk cost: XvTc 4*576*2 + A 4096*2 = 12800 B.
    long long Nc = N_TOT;
    {
        long long spare = (long long)ws_size - (long long)fixed;
        long long cap = spare / 12800;
        cap = (cap / 768) * 768;          // lcm(256,6,128) alignment
        if (cap < 768) cap = 768;
        if (cap > N_TOT) cap = N_TOT;
        Nc = cap;
    }

    unsigned short* S    = (unsigned short*)(ws);
    unsigned short* W2b  = (unsigned short*)(ws + szS);
    float*          yT   = (float*)(ws + szS + szW2);
    unsigned short* XvTc = (unsigned short*)(ws + fixed);
    unsigned short* A    = (unsigned short*)(ws + fixed + (size_t)4 * FEAT * Nc * 2);

    k_norms<<<dim3(B_TOT), 256, 0, stream>>>(x, S);
    k_w2<<<dim3(64, 9, 4), 256, 0, stream>>>((const float*)d_in[1], (const float*)d_in[2],
                                             (const float*)d_in[3], (const float*)d_in[4], W2b);

    for (long long c0 = 0; c0 < N_TOT; c0 += Nc) {
        const int nc = (int)((N_TOT - c0 < Nc) ? (N_TOT - c0) : Nc);
        k_xvt<<<dim3(nc / 64, FEAT / 32), 256, 0, stream>>>(x, XvTc, (int)c0, nc);
        for (int v = 0; v < 4; ++v) {
            const unsigned short* Sv = S + (size_t)v * N_TOT * NCH;
            const unsigned short* Xv = XvTc + (size_t)v * FEAT * nc;
            for (int k = 0; k < 3; ++k) {
                const unsigned short* Wvk = W2b + (size_t)(v * 3 + k) * CDIM * KD;
                k_gemm1<<<dim3(nc / 128, 32), 256, 0, stream>>>(Sv, Wvk, A, (int)c0, nc);
                if (k == 0)
                    k_gemm2<1><<<dim3(nc / 256, 8), 256, 0, stream>>>(A, Xv, yT, (int)c0, nc, 0, v > 0);
                else if (k == 1)
                    k_gemm2<3><<<dim3(nc / 256, 8), 256, 0, stream>>>(A, Xv, yT, (int)c0, nc, 64, v > 0);
                else
                    k_gemm2<5><<<dim3(nc / 256, 8), 256, 0, stream>>>(A, Xv, yT, (int)c0, nc, 256, v > 0);
            }
        }
    }
    k_out<<<dim3(N_TOT / 64, FEAT / 32), 256, 0, stream>>>(yT, out);
}